// Round 8
// baseline (130.834 us; speedup 1.0000x reference)
//
#include <hip/hip_runtime.h>
#include <hip/hip_bf16.h>

typedef __attribute__((ext_vector_type(4))) int i32x4;

#define M_DIM 8192
#define K_DIM 1024
#define N_DIM 4096
#define OUT_ELEMS (M_DIM * (size_t)N_DIM)

static __device__ __forceinline__ void gload_lds16(const void* g, void* l) {
  __builtin_amdgcn_global_load_lds((__attribute__((address_space(1))) void*)g,
                                   (__attribute__((address_space(3))) void*)l,
                                   16, 0, 0);
}

// monotone float<->uint encoding for atomic min/max
static __device__ __forceinline__ unsigned enc(float f) {
  unsigned u = __float_as_uint(f);
  return (u >> 31) ? ~u : (u ^ 0x80000000u);
}
static __device__ __forceinline__ float dec(unsigned e) {
  return (e >> 31) ? __uint_as_float(e ^ 0x80000000u) : __uint_as_float(~e);
}

// pack 4 int-valued floats into one i32 as signed bytes (unsigned shifts: no UB)
static __device__ __forceinline__ int pack4(float a, float b, float c, float d) {
  unsigned v0 = (unsigned)(int)a & 255u, v1 = (unsigned)(int)b & 255u;
  unsigned v2 = (unsigned)(int)c & 255u, v3 = (unsigned)(int)d & 255u;
  return (int)(v0 | (v1 << 8) | (v2 << 16) | (v3 << 24));
}

// -------- Kernel A: per-channel weight quant (int8) + IntGELU per-channel constants ----
__global__ __launch_bounds__(256) void k_prep_w(
    const float* __restrict__ w, const float* __restrict__ bias,
    const float* __restrict__ prev_sf,
    int* __restrict__ wq, float* __restrict__ pb, float* __restrict__ pbg,
    float* __restrict__ pcg, float* __restrict__ psh, float* __restrict__ posf,
    unsigned* __restrict__ mm) {
  const int o = blockIdx.x;
  const int t = threadIdx.x;
  const float4 wv = *(const float4*)(w + (size_t)o * K_DIM + t * 4);
  float m = fmaxf(fmaxf(fabsf(wv.x), fabsf(wv.y)), fmaxf(fabsf(wv.z), fabsf(wv.w)));
  __shared__ float red[256];
  red[t] = m;
  __syncthreads();
  for (int s = 128; s > 0; s >>= 1) {
    if (t < s) red[t] = fmaxf(red[t], red[t + s]);
    __syncthreads();
  }
  const float fc = fmaxf(red[0], 1e-8f) / 127.f;  // fc_sf[o]
  wq[o * (K_DIM / 4) + t] = pack4(
      fminf(fmaxf(rintf(wv.x / fc), -127.f), 126.f),
      fminf(fmaxf(rintf(wv.y / fc), -127.f), 126.f),
      fminf(fmaxf(rintf(wv.z / fc), -127.f), 126.f),
      fminf(fmaxf(rintf(wv.w / fc), -127.f), 126.f));
  if (t == 0) {
    const float psf = prev_sf[0];
    const float bsf = fc * psf;  // bias_sf
    float bi = fminf(fmaxf(rintf(bias[o] / bsf), -2147483647.f), 2147483646.f);
    const float sfe = bsf / 1.4142f;
    const float bg = floorf(-1.769f / sfe);
    const float cF = (float)(1.0 / -0.2888);
    const float se2 = sfe * sfe;
    const float cg = floorf(cF / se2);
    const float sig = (se2 * -0.2888f) * 16384.f;   // sf_e^2 * a * 2^14
    const float sh = floorf(1.0f / sig);            // shift (negative)
    const float osf = (bsf * sig) * 0.5f;           // out_sf (negative)
    pb[o] = bi; pbg[o] = bg; pcg[o] = cg; psh[o] = sh; posf[o] = osf;
  }
  if (o == 0 && t == 0) {  // init global min/max (encoded 0.0f)
    mm[0] = 0x80000000u;
    mm[1] = 0x80000000u;
  }
}

// -------- Kernel B: activation -> exact-integer int8 --------
__global__ __launch_bounds__(256) void k_quant_x(
    const float* __restrict__ x, const float* __restrict__ prev_sf,
    int4* __restrict__ xq) {
  const size_t i = ((size_t)blockIdx.x * 256 + threadIdx.x) * 16;
  const float inv = 1.0f / prev_sf[0];
  const float4 v0 = *(const float4*)(x + i);
  const float4 v1 = *(const float4*)(x + i + 4);
  const float4 v2 = *(const float4*)(x + i + 8);
  const float4 v3 = *(const float4*)(x + i + 12);
  int4 q;
  q.x = pack4(rintf(v0.x * inv), rintf(v0.y * inv), rintf(v0.z * inv), rintf(v0.w * inv));
  q.y = pack4(rintf(v1.x * inv), rintf(v1.y * inv), rintf(v1.z * inv), rintf(v1.w * inv));
  q.z = pack4(rintf(v2.x * inv), rintf(v2.y * inv), rintf(v2.z * inv), rintf(v2.w * inv));
  q.w = pack4(rintf(v3.x * inv), rintf(v3.y * inv), rintf(v3.z * inv), rintf(v3.w * inv));
  xq[i / 16] = q;
}

// -------- Kernel C: int8 MFMA GEMM (exact i32) + fused bias/IntGELU/minmax, f32 out ----
// R8: 128x128 tile, 4 waves (2Mx2N), BK=128, LDS 64KB ring-2 -> 2 BLOCKS/CU.
// The drain-0 schedule is kept (R4-proven); cross-block overlap (m114) hides the
// per-phase vmcnt/lgkmcnt drains that scheduling tweaks (R5/R7) could not.
// Slot = [128 rows][128B] (8 chunks of 16B), chunk swizzle c' = c ^ (row&7) via
// pre-swizzled global source (LDS dest linear, rule #21); measured 0 conflicts (R4).
__global__ __launch_bounds__(256, 2) void k_gemm(
    const char* __restrict__ A, const char* __restrict__ B,
    const float* __restrict__ pb, const float* __restrict__ pbg,
    const float* __restrict__ pcg, const float* __restrict__ psh,
    const float* __restrict__ posf,
    float* __restrict__ out, unsigned* __restrict__ mm) {
  __shared__ __align__(16) char smem[65536];   // A ring 2x16KB | B ring 2x16KB
  __shared__ float smn[4], smx[4];
  const int t = threadIdx.x;
  const int wave = t >> 6, lane = t & 63;
  const int wm = wave >> 1, wn = wave & 1;          // 2x2 wave grid
  const int r16 = lane & 15, q4 = lane >> 4;
  // XCD-local 16x16 (M,N) sub-grid: per-XCD working set = 2MB A + 2MB B = 4MB = L2
  const int lin = blockIdx.x;
  const int xcd = lin & 7, j = lin >> 3;            // j in [0,256)
  const int mblk = (xcd >> 1) * 16 + (j >> 4);      // [0,64)
  const int nblk = (xcd & 1) * 16 + (j & 15);       // [0,32)
  const int brow = mblk * 128, bcol = nblk * 128;
  // staging constants: window = 32 rows x 128B; source chunk pre-swizzled
  const int sr = t >> 3;                             // row in 32-row window
  const int sc = (t & 7) ^ (sr & 7);                 // swizzled 16B chunk
  // ds_read constants
  const int cs0 = (q4 ^ (r16 & 7)) * 16;             // kk=0 chunk byte
  const int cs1 = ((4 + q4) ^ (r16 & 7)) * 16;       // kk=1 chunk byte
  const int aB = (wm * 64 + r16) * 128;
  const int bB = 32768 + (wn * 64 + r16) * 128;
  i32x4 acc[4][4] = {};

  auto stage = [&](int s) {
    const int ring = (s & 1) << 14;
    const int kof = s * 128;
#pragma unroll
    for (int w = 0; w < 4; ++w) {
      const int row = w * 32 + sr;
      gload_lds16(A + (size_t)(brow + row) * K_DIM + kof + sc * 16,
                  smem + ring + row * 128);
      gload_lds16(B + (size_t)(bcol + row) * K_DIM + kof + sc * 16,
                  smem + 32768 + ring + row * 128);
    }
  };

  stage(0);
  asm volatile("s_waitcnt vmcnt(0)" ::: "memory");
  __builtin_amdgcn_s_barrier();

  for (int s = 0; s < 8; ++s) {
    if (s < 7) stage(s + 1);
    const int ring = (s & 1) << 14;
#pragma unroll
    for (int kk = 0; kk < 2; ++kk) {
      const int cs = kk ? cs1 : cs0;
      i32x4 af[4], bfr[4];
#pragma unroll
      for (int nf = 0; nf < 4; ++nf)
        bfr[nf] = *(const i32x4*)(smem + ring + bB + nf * 2048 + cs);
#pragma unroll
      for (int mf = 0; mf < 4; ++mf)
        af[mf] = *(const i32x4*)(smem + ring + aB + mf * 2048 + cs);
      __builtin_amdgcn_s_setprio(1);
#pragma unroll
      for (int mf = 0; mf < 4; ++mf)
#pragma unroll
        for (int nf = 0; nf < 4; ++nf)
          acc[mf][nf] = __builtin_amdgcn_mfma_i32_16x16x64_i8(af[mf], bfr[nf], acc[mf][nf], 0, 0, 0);
      __builtin_amdgcn_s_setprio(0);
    }
    asm volatile("s_waitcnt vmcnt(0) lgkmcnt(0)" ::: "memory");
    __builtin_amdgcn_s_barrier();
  }

  // epilogue: bias add + IntGELU, write pre-requant f32 value, track min/max
  float mn = 0.f, mx = 0.f;
#pragma unroll
  for (int nf = 0; nf < 4; ++nf) {
    const int ch = bcol + wn * 64 + nf * 16 + r16;
    const float bi = pb[ch], bg = pbg[ch], cg = pcg[ch], sh = psh[ch], osf = posf[ch];
#pragma unroll
    for (int mf = 0; mf < 4; ++mf) {
      const int row0 = brow + wm * 64 + mf * 16 + q4 * 4;
#pragma unroll
      for (int r = 0; r < 4; ++r) {
        const float x0 = (float)acc[mf][nf][r] + bi;             // out_int (exact, <2^24)
        const float sgn = (x0 > 0.f) ? 1.f : ((x0 < 0.f) ? -1.f : 0.f);
        const float ai = fminf(fabsf(x0), -bg);
        const float tt = ai + bg;
        const float y = floorf((sgn * (tt * tt + cg)) * 6.103515625e-05f);  // /2^14
        const float xval = (x0 * (y + sh)) * osf;
        mn = fminf(mn, xval);
        mx = fmaxf(mx, xval);
        out[(size_t)(row0 + r) * N_DIM + ch] = xval;
      }
    }
  }
  for (int off = 32; off > 0; off >>= 1) {
    mn = fminf(mn, __shfl_down(mn, off));
    mx = fmaxf(mx, __shfl_down(mx, off));
  }
  if (lane == 0) { smn[wave] = mn; smx[wave] = mx; }
  __syncthreads();
  if (t == 0) {
    mn = fminf(fminf(smn[0], smn[1]), fminf(smn[2], smn[3]));
    mx = fmaxf(fmaxf(smx[0], smx[1]), fmaxf(smx[2], smx[3]));
    atomicMin(&mm[0], enc(mn));
    atomicMax(&mm[1], enc(mx));
  }
}

// -------- Kernel D: global requant (QuantAct / FixedPointMul), in place on d_out ------
__global__ __launch_bounds__(256) void k_requant(
    float* __restrict__ out, const float* __restrict__ posf,
    const unsigned* __restrict__ mm) {
  const float xmn = dec(mm[0]);
  const float xmx = dec(mm[1]);
  const float asf = fmaxf(fmaxf(fabsf(xmn), fabsf(xmx)), 1e-8f) / 127.f;
  const size_t i = ((size_t)blockIdx.x * 256 + threadIdx.x) * 4;
  float4 xv = *(float4*)(out + i);
  const int o0 = (int)(i & (N_DIM - 1));
  const float4 sf4 = *(const float4*)(posf + o0);
  float xs[4] = {xv.x, xv.y, xv.z, xv.w};
  float ps[4] = {sf4.x, sf4.y, sf4.z, sf4.w};
  float rs[4];
#pragma unroll
  for (int r = 0; r < 4; ++r) {
    const float z = rintf(xs[r] / ps[r]);
    int e;
    const float mfr = frexpf(ps[r] / asf, &e);
    const float mi = floorf(mfr * 2147483648.f + 0.5f);
    float q = rintf((z * mi) * ldexpf(1.0f, e - 31));
    q = fminf(fmaxf(q, -128.f), 127.f);
    rs[r] = q * asf;
  }
  xv.x = rs[0]; xv.y = rs[1]; xv.z = rs[2]; xv.w = rs[3];
  *(float4*)(out + i) = xv;
  if (blockIdx.x == 0 && threadIdx.x == 0) out[OUT_ELEMS] = asf;  // trailing sf scalar
}

extern "C" void kernel_launch(void* const* d_in, const int* in_sizes, int n_in,
                              void* d_out, int out_size, void* d_ws, size_t ws_size,
                              hipStream_t stream) {
  const float* x = (const float*)d_in[0];
  const float* psf = (const float*)d_in[1];
  const float* w = (const float*)d_in[2];
  const float* bias = (const float*)d_in[3];
  float* out = (float*)d_out;
  char* ws = (char*)d_ws;

  int* wq = (int*)ws;                                     // 4 MiB (i8)
  char* xq = ws + 4194304;                                // 8 MiB (i8)
  float* pb = (float*)(ws + 12582912);                    // 5 x 16 KiB
  float* pbg = pb + N_DIM;
  float* pcg = pb + 2 * N_DIM;
  float* psh = pb + 3 * N_DIM;
  float* posf = pb + 4 * N_DIM;
  unsigned* mm = (unsigned*)(pb + 5 * N_DIM + 16);        // 2 x u32 min/max

  k_prep_w<<<dim3(N_DIM), dim3(256), 0, stream>>>(w, bias, psf, wq, pb, pbg, pcg, psh, posf, mm);
  k_quant_x<<<dim3((M_DIM * K_DIM) / (256 * 16)), dim3(256), 0, stream>>>(x, psf, (int4*)xq);
  k_gemm<<<dim3(2048), dim3(256), 0, stream>>>(xq, (const char*)wq, pb, pbg, pcg, psh, posf, out, mm);
  k_requant<<<dim3((int)(OUT_ELEMS / (256 * 4))), dim3(256), 0, stream>>>(out, posf, mm);
}

// Round 9
// 120.961 us; speedup vs baseline: 1.0816x; 1.0816x over previous
//
#include <hip/hip_runtime.h>
#include <hip/hip_bf16.h>

typedef __attribute__((ext_vector_type(4))) int i32x4;

#define M_DIM 8192
#define K_DIM 1024
#define N_DIM 4096
#define OUT_ELEMS (M_DIM * (size_t)N_DIM)

static __device__ __forceinline__ void gload_lds16(const void* g, void* l) {
  __builtin_amdgcn_global_load_lds((__attribute__((address_space(1))) void*)g,
                                   (__attribute__((address_space(3))) void*)l,
                                   16, 0, 0);
}

// monotone float<->uint encoding for atomic min/max
static __device__ __forceinline__ unsigned enc(float f) {
  unsigned u = __float_as_uint(f);
  return (u >> 31) ? ~u : (u ^ 0x80000000u);
}
static __device__ __forceinline__ float dec(unsigned e) {
  return (e >> 31) ? __uint_as_float(e ^ 0x80000000u) : __uint_as_float(~e);
}

// pack 4 int-valued floats into one i32 as signed bytes (unsigned shifts: no UB)
static __device__ __forceinline__ int pack4(float a, float b, float c, float d) {
  unsigned v0 = (unsigned)(int)a & 255u, v1 = (unsigned)(int)b & 255u;
  unsigned v2 = (unsigned)(int)c & 255u, v3 = (unsigned)(int)d & 255u;
  return (int)(v0 | (v1 << 8) | (v2 << 16) | (v3 << 24));
}

// -------- Kernel A: per-channel weight quant (int8) + IntGELU per-channel constants ----
__global__ __launch_bounds__(256) void k_prep_w(
    const float* __restrict__ w, const float* __restrict__ bias,
    const float* __restrict__ prev_sf,
    int* __restrict__ wq, float* __restrict__ pb, float* __restrict__ pbg,
    float* __restrict__ pcg, float* __restrict__ psh, float* __restrict__ posf,
    unsigned* __restrict__ mm) {
  const int o = blockIdx.x;
  const int t = threadIdx.x;
  const float4 wv = *(const float4*)(w + (size_t)o * K_DIM + t * 4);
  float m = fmaxf(fmaxf(fabsf(wv.x), fabsf(wv.y)), fmaxf(fabsf(wv.z), fabsf(wv.w)));
  __shared__ float red[256];
  red[t] = m;
  __syncthreads();
  for (int s = 128; s > 0; s >>= 1) {
    if (t < s) red[t] = fmaxf(red[t], red[t + s]);
    __syncthreads();
  }
  const float fc = fmaxf(red[0], 1e-8f) / 127.f;  // fc_sf[o]
  wq[o * (K_DIM / 4) + t] = pack4(
      fminf(fmaxf(rintf(wv.x / fc), -127.f), 126.f),
      fminf(fmaxf(rintf(wv.y / fc), -127.f), 126.f),
      fminf(fmaxf(rintf(wv.z / fc), -127.f), 126.f),
      fminf(fmaxf(rintf(wv.w / fc), -127.f), 126.f));
  if (t == 0) {
    const float psf = prev_sf[0];
    const float bsf = fc * psf;  // bias_sf
    float bi = fminf(fmaxf(rintf(bias[o] / bsf), -2147483647.f), 2147483646.f);
    const float sfe = bsf / 1.4142f;
    const float bg = floorf(-1.769f / sfe);
    const float cF = (float)(1.0 / -0.2888);
    const float se2 = sfe * sfe;
    const float cg = floorf(cF / se2);
    const float sig = (se2 * -0.2888f) * 16384.f;   // sf_e^2 * a * 2^14
    const float sh = floorf(1.0f / sig);            // shift (negative)
    const float osf = (bsf * sig) * 0.5f;           // out_sf (negative)
    pb[o] = bi; pbg[o] = bg; pcg[o] = cg; psh[o] = sh; posf[o] = osf;
  }
  if (o == 0 && t == 0) {  // init global min/max (encoded 0.0f)
    mm[0] = 0x80000000u;
    mm[1] = 0x80000000u;
  }
}

// -------- Kernel B: activation -> exact-integer int8 --------
__global__ __launch_bounds__(256) void k_quant_x(
    const float* __restrict__ x, const float* __restrict__ prev_sf,
    int4* __restrict__ xq) {
  const size_t i = ((size_t)blockIdx.x * 256 + threadIdx.x) * 16;
  const float inv = 1.0f / prev_sf[0];
  const float4 v0 = *(const float4*)(x + i);
  const float4 v1 = *(const float4*)(x + i + 4);
  const float4 v2 = *(const float4*)(x + i + 8);
  const float4 v3 = *(const float4*)(x + i + 12);
  int4 q;
  q.x = pack4(rintf(v0.x * inv), rintf(v0.y * inv), rintf(v0.z * inv), rintf(v0.w * inv));
  q.y = pack4(rintf(v1.x * inv), rintf(v1.y * inv), rintf(v1.z * inv), rintf(v1.w * inv));
  q.z = pack4(rintf(v2.x * inv), rintf(v2.y * inv), rintf(v2.z * inv), rintf(v2.w * inv));
  q.w = pack4(rintf(v3.x * inv), rintf(v3.y * inv), rintf(v3.z * inv), rintf(v3.w * inv));
  xq[i / 16] = q;
}

// -------- Kernel C: int8 MFMA GEMM, m201-style fine-phase pipeline (i8 port) ----------
// 256x256 tile, 8 waves (2Mx4N). K = 16 tiles of 64 bytes. LDS ring-4 x (A 16KB +
// B 16KB) = 128KB. Row = 64B (4 chunks of 16B), swizzle chunk' = q4 ^ ((row>>1)&3)
// (R2/R4 measured-zero pattern) via pre-swizzled global source (LDS dest linear).
// Per K-tile, TWO phases, each: {ds_read 4-8 frags -> stage 2 gload_lds (tile kt+3,
// into slot freed at kt-1; per-phase lgkmcnt(0) drains make it WAR-safe) -> barrier ->
// lgkmcnt(0) -> sched_barrier -> 16 MFMA (setprio) -> barrier}. vmcnt(8) once per
// K-tile (tiles kt+2,kt+3 = 8 loads stay in flight; tail 4 -> 0). Never drain mid-loop.
__global__ __launch_bounds__(512, 2) void k_gemm(
    const char* __restrict__ A, const char* __restrict__ B,
    const float* __restrict__ pb, const float* __restrict__ pbg,
    const float* __restrict__ pcg, const float* __restrict__ psh,
    const float* __restrict__ posf,
    float* __restrict__ out, unsigned* __restrict__ mm) {
  __shared__ __align__(16) char smem[131072];
  __shared__ float smn[8], smx[8];
  const int t = threadIdx.x;
  const int wave = t >> 6, lane = t & 63;
  const int wm = wave >> 2, wn = wave & 3;          // 2x4 wave grid
  const int r16 = lane & 15, q4 = lane >> 4;
  // XCD-local 8x8 (M,N) sub-grid: per-XCD working set = 2MB A + 2MB B = 4MB = L2
  const int lin = blockIdx.x;
  const int xcd = lin & 7, j = lin >> 3;
  const int mblk = (xcd >> 1) * 8 + (j >> 3);       // [0,32)
  const int nblk = (xcd & 1) * 8 + (j & 7);         // [0,16)
  const int brow = mblk * 256, bcol = nblk * 256;
  // staging constants (per thread): row = t>>2 within 128-row half, src chunk pre-swz
  const int strow = t >> 2;
  const int sc16 = ((t & 3) ^ ((t >> 3) & 3)) << 4;
  // ds_read constants: addr = ring + base + frag*1024; swz = q4 ^ ((r16>>1)&3)
  const int swz16 = (q4 ^ ((r16 >> 1) & 3)) << 4;
  const int aBase = (wm * 128 + r16) * 64 + swz16;
  const int bBase = 16384 + (wn * 64 + r16) * 64 + swz16;
  i32x4 acc[8][4] = {};

  auto stageA = [&](int tile) {
    const int ring = (tile & 3) << 15;
    const int kof = tile << 6;
    gload_lds16(A + (size_t)(brow + strow) * K_DIM + kof + sc16,
                smem + ring + t * 16);
    gload_lds16(A + (size_t)(brow + 128 + strow) * K_DIM + kof + sc16,
                smem + ring + 8192 + t * 16);
  };
  auto stageB = [&](int tile) {
    const int ring = (tile & 3) << 15;
    const int kof = tile << 6;
    gload_lds16(B + (size_t)(bcol + strow) * K_DIM + kof + sc16,
                smem + ring + 16384 + t * 16);
    gload_lds16(B + (size_t)(bcol + 128 + strow) * K_DIM + kof + sc16,
                smem + ring + 24576 + t * 16);
  };

  // prologue: stage tiles 0,1,2 (12 loads); wait until tile 0 landed (8 in flight)
  stageA(0); stageB(0);
  stageA(1); stageB(1);
  stageA(2); stageB(2);
  asm volatile("s_waitcnt vmcnt(8)" ::: "memory");
  asm volatile("s_barrier" ::: "memory");

  for (int kt = 0; kt < 16; ++kt) {
    const int ring = (kt & 3) << 15;
    // ================= phase 0: mf 0-3 =================
    i32x4 af[4], bfr[4];
#pragma unroll
    for (int mf = 0; mf < 4; ++mf)
      af[mf] = *(const i32x4*)(smem + ring + aBase + mf * 1024);
#pragma unroll
    for (int nf = 0; nf < 4; ++nf)
      bfr[nf] = *(const i32x4*)(smem + ring + bBase + nf * 1024);
    if (kt <= 12) stageA(kt + 3);
    asm volatile("s_barrier" ::: "memory");
    asm volatile("s_waitcnt lgkmcnt(0)" ::: "memory");
    __builtin_amdgcn_sched_barrier(0);
    __builtin_amdgcn_s_setprio(1);
#pragma unroll
    for (int mf = 0; mf < 4; ++mf)
#pragma unroll
      for (int nf = 0; nf < 4; ++nf)
        acc[mf][nf] = __builtin_amdgcn_mfma_i32_16x16x64_i8(af[mf], bfr[nf], acc[mf][nf], 0, 0, 0);
    __builtin_amdgcn_s_setprio(0);
    __builtin_amdgcn_sched_barrier(0);
    asm volatile("s_barrier" ::: "memory");
    // ================= phase 1: mf 4-7 =================
    i32x4 af2[4];
#pragma unroll
    for (int mf = 0; mf < 4; ++mf)
      af2[mf] = *(const i32x4*)(smem + ring + aBase + (4 + mf) * 1024);
    if (kt <= 12) stageB(kt + 3);
    if (kt <= 12) {
      asm volatile("s_waitcnt vmcnt(8)" ::: "memory");   // tile kt+1 landed
    } else if (kt == 13) {
      asm volatile("s_waitcnt vmcnt(4)" ::: "memory");   // tile 14 landed
    } else {
      asm volatile("s_waitcnt vmcnt(0)" ::: "memory");   // tile 15 landed
    }
    asm volatile("s_barrier" ::: "memory");
    asm volatile("s_waitcnt lgkmcnt(0)" ::: "memory");
    __builtin_amdgcn_sched_barrier(0);
    __builtin_amdgcn_s_setprio(1);
#pragma unroll
    for (int mf = 0; mf < 4; ++mf)
#pragma unroll
      for (int nf = 0; nf < 4; ++nf)
        acc[4 + mf][nf] = __builtin_amdgcn_mfma_i32_16x16x64_i8(af2[mf], bfr[nf], acc[4 + mf][nf], 0, 0, 0);
    __builtin_amdgcn_s_setprio(0);
    __builtin_amdgcn_sched_barrier(0);
    asm volatile("s_barrier" ::: "memory");
  }

  // epilogue: bias add + IntGELU, write pre-requant f32 value, track min/max
  float mn = 0.f, mx = 0.f;
#pragma unroll
  for (int nf = 0; nf < 4; ++nf) {
    const int ch = bcol + wn * 64 + nf * 16 + r16;
    const float bi = pb[ch], bg = pbg[ch], cg = pcg[ch], sh = psh[ch], osf = posf[ch];
#pragma unroll
    for (int mf = 0; mf < 8; ++mf) {
      const int row0 = brow + wm * 128 + mf * 16 + q4 * 4;
#pragma unroll
      for (int r = 0; r < 4; ++r) {
        const float x0 = (float)acc[mf][nf][r] + bi;             // out_int (exact, <2^24)
        const float sgn = (x0 > 0.f) ? 1.f : ((x0 < 0.f) ? -1.f : 0.f);
        const float ai = fminf(fabsf(x0), -bg);
        const float tt = ai + bg;
        const float y = floorf((sgn * (tt * tt + cg)) * 6.103515625e-05f);  // /2^14
        const float xval = (x0 * (y + sh)) * osf;
        mn = fminf(mn, xval);
        mx = fmaxf(mx, xval);
        out[(size_t)(row0 + r) * N_DIM + ch] = xval;
      }
    }
  }
  for (int off = 32; off > 0; off >>= 1) {
    mn = fminf(mn, __shfl_down(mn, off));
    mx = fmaxf(mx, __shfl_down(mx, off));
  }
  if (lane == 0) { smn[wave] = mn; smx[wave] = mx; }
  __syncthreads();
  if (t == 0) {
    mn = fminf(fminf(fminf(smn[0], smn[1]), fminf(smn[2], smn[3])),
               fminf(fminf(smn[4], smn[5]), fminf(smn[6], smn[7])));
    mx = fmaxf(fmaxf(fmaxf(smx[0], smx[1]), fmaxf(smx[2], smx[3])),
               fmaxf(fmaxf(smx[4], smx[5]), fmaxf(smx[6], smx[7])));
    atomicMin(&mm[0], enc(mn));
    atomicMax(&mm[1], enc(mx));
  }
}

// -------- Kernel D: global requant (QuantAct / FixedPointMul), in place on d_out ------
__global__ __launch_bounds__(256) void k_requant(
    float* __restrict__ out, const float* __restrict__ posf,
    const unsigned* __restrict__ mm) {
  const float xmn = dec(mm[0]);
  const float xmx = dec(mm[1]);
  const float asf = fmaxf(fmaxf(fabsf(xmn), fabsf(xmx)), 1e-8f) / 127.f;
  const size_t i = ((size_t)blockIdx.x * 256 + threadIdx.x) * 4;
  float4 xv = *(float4*)(out + i);
  const int o0 = (int)(i & (N_DIM - 1));
  const float4 sf4 = *(const float4*)(posf + o0);
  float xs[4] = {xv.x, xv.y, xv.z, xv.w};
  float ps[4] = {sf4.x, sf4.y, sf4.z, sf4.w};
  float rs[4];
#pragma unroll
  for (int r = 0; r < 4; ++r) {
    const float z = rintf(xs[r] / ps[r]);
    int e;
    const float mfr = frexpf(ps[r] / asf, &e);
    const float mi = floorf(mfr * 2147483648.f + 0.5f);
    float q = rintf((z * mi) * ldexpf(1.0f, e - 31));
    q = fminf(fmaxf(q, -128.f), 127.f);
    rs[r] = q * asf;
  }
  xv.x = rs[0]; xv.y = rs[1]; xv.z = rs[2]; xv.w = rs[3];
  *(float4*)(out + i) = xv;
  if (blockIdx.x == 0 && threadIdx.x == 0) out[OUT_ELEMS] = asf;  // trailing sf scalar
}

extern "C" void kernel_launch(void* const* d_in, const int* in_sizes, int n_in,
                              void* d_out, int out_size, void* d_ws, size_t ws_size,
                              hipStream_t stream) {
  const float* x = (const float*)d_in[0];
  const float* psf = (const float*)d_in[1];
  const float* w = (const float*)d_in[2];
  const float* bias = (const float*)d_in[3];
  float* out = (float*)d_out;
  char* ws = (char*)d_ws;

  int* wq = (int*)ws;                                     // 4 MiB (i8)
  char* xq = ws + 4194304;                                // 8 MiB (i8)
  float* pb = (float*)(ws + 12582912);                    // 5 x 16 KiB
  float* pbg = pb + N_DIM;
  float* pcg = pb + 2 * N_DIM;
  float* psh = pb + 3 * N_DIM;
  float* posf = pb + 4 * N_DIM;
  unsigned* mm = (unsigned*)(pb + 5 * N_DIM + 16);        // 2 x u32 min/max

  k_prep_w<<<dim3(N_DIM), dim3(256), 0, stream>>>(w, bias, psf, wq, pb, pbg, pcg, psh, posf, mm);
  k_quant_x<<<dim3((M_DIM * K_DIM) / (256 * 16)), dim3(256), 0, stream>>>(x, psf, (int4*)xq);
  k_gemm<<<dim3(512), dim3(512), 0, stream>>>(xq, (const char*)wq, pb, pbg, pcg, psh, posf, out, mm);
  k_requant<<<dim3((int)(OUT_ELEMS / (256 * 4))), dim3(256), 0, stream>>>(out, posf, mm);
}